// Round 17
// baseline (319.266 us; speedup 1.0000x reference)
//
#include <hip/hip_runtime.h>
#include <hip/hip_bf16.h>

typedef __bf16 bf16x8 __attribute__((ext_vector_type(8)));
typedef float f32x4 __attribute__((ext_vector_type(4)));

static constexpr int Tn = 8192;
static constexpr int Cn = 1024;

#define DEVI __device__ __forceinline__

DEVI float bf2f(ushort u) { union { uint i; float f; } c; c.i = ((uint)u) << 16; return c.f; }
DEVI ushort f2bf(float f) {
  uint x = __builtin_bit_cast(uint, f);
  x += 0x7fffu + ((x >> 16) & 1u);   // RNE
  return (ushort)(x >> 16);
}

typedef const __attribute__((address_space(1))) void glb_v;
typedef __attribute__((address_space(3))) void lds_v;

// ---------------------------------------------------------------- cast + concat + l-zero
__global__ __launch_bounds__(256) void cast_all(
    const float* __restrict__ x, const float* __restrict__ wq, const float* __restrict__ wk,
    const float* __restrict__ wv, const float* __restrict__ wp,
    const float* __restrict__ bq, const float* __restrict__ bk, const float* __restrict__ bv,
    ushort* __restrict__ xb, ushort* __restrict__ wqkv, ushort* __restrict__ wpb,
    float* __restrict__ bqkv, float* __restrict__ lsum)
{
  const long long NX = (long long)Tn * Cn;
  const long long NW = (long long)Cn * Cn;      // 2^20
  if (blockIdx.x == 12291) {   // zero the softmax-denominator accumulator
    float4 z; z.x = z.y = z.z = z.w = 0.f;
#pragma unroll
    for (int j = 0; j < 8; ++j) ((float4*)lsum)[threadIdx.x * 8 + j] = z;
    return;
  }
  if (blockIdx.x >= 12288) {   // bias concat (3 blocks)
    int id = ((blockIdx.x - 12288) * 256 + threadIdx.x) * 4;
#pragma unroll
    for (int e = 0; e < 4; ++e) {
      int j = id + e;
      if (j < 3 * Cn) bqkv[j] = j < Cn ? bq[j] : (j < 2 * Cn ? bk[j - Cn] : bv[j - 2 * Cn]);
    }
    return;
  }
  long long i = ((long long)blockIdx.x * 256 + threadIdx.x) * 4;
  const float* src; ushort* dst; long long off;
  if (i < NX) { src = x; dst = xb; off = i; }
  else {
    long long r = i - NX; int seg = (int)(r >> 20); off = r & (NW - 1);
    if (seg < 3) { src = seg == 0 ? wq : seg == 1 ? wk : wv; dst = wqkv + (size_t)seg * NW; }
    else         { src = wp; dst = wpb; }
  }
  float4 v = *reinterpret_cast<const float4*>(src + off);
  ushort4 o; o.x = f2bf(v.x); o.y = f2bf(v.y); o.z = f2bf(v.z); o.w = f2bf(v.w);
  *reinterpret_cast<ushort4*>(dst + off) = o;
}

// ---------------------------------------------------------------- Y = (P0 + P1) / lsum -> bf16
__global__ __launch_bounds__(256) void ydiv(const ushort* __restrict__ P0,
                                            const ushort* __restrict__ P1,
                                            const float* __restrict__ lsum,
                                            ushort* __restrict__ Yb)
{
  const int i = (blockIdx.x * 256 + threadIdx.x) * 8;     // 8 elems, same row
  const int row = i >> 10;
  const float inv = 1.0f / lsum[row];
  uint4 a = *reinterpret_cast<const uint4*>(P0 + i);
  uint4 b = *reinterpret_cast<const uint4*>(P1 + i);
  const ushort* ua = reinterpret_cast<const ushort*>(&a);
  const ushort* ub = reinterpret_cast<const ushort*>(&b);
  union { uint4 v; ushort u[8]; } pk;
#pragma unroll
  for (int e = 0; e < 8; ++e) pk.u[e] = f2bf((bf2f(ua[e]) + bf2f(ub[e])) * inv);
  *reinterpret_cast<uint4*>(Yb + i) = pk.v;
}

// ---------------------------------------------------------------- plain-HIP GEMM engine
// NO inline assembly anywhere: single 32KB LDS buffer, stage via
// __builtin_amdgcn_global_load_lds (width 16), __syncthreads() ordering
// (compiler inserts the vmcnt/lgkmcnt drains). This is the R1/R5-verified
// engine body. 128x128 tile, 4 waves (2x2, per-wave 64x64), BK=64,
// chunk-XOR LDS swizzle (0 bank conflicts, verified R1-R11).
// QKT: supertiled triangular dispatch (8-column groups, row-major inside:
//      consecutive blocks share the Q panel, the group's 8 K panels stay
//      L2-warm). Epilogue exp(s/32)+mask -> S bf16 + atomic row-sums lsum.
// PVM: 1-D grid 1024, split-K=2 (z=id&1, exact halves of the causal range),
//      bf16 partials to outp/outp2 (disjoint, no atomics), longest rows first.
template<bool OUT_BF16, bool HAS_BIAS, bool QKT, bool PVM, bool SPLIT3>
__global__ __launch_bounds__(256)
void gemm_pl(const ushort* __restrict__ A, const ushort* __restrict__ Bt,
             const float* __restrict__ bias, void* __restrict__ outp,
             void* __restrict__ outp2, float* __restrict__ lsum,
             int K, int lda, int ldb, int ldc, float scale)
{
  __shared__ __align__(16) ushort Als[128 * 64];
  __shared__ __align__(16) ushort Bls[128 * 64];

  const int tid = threadIdx.x, lane = tid & 63, wid = tid >> 6;
  const int wr = (wid >> 1) * 64, wc = (wid & 1) * 64;
  const int ln15 = lane & 15, lhi = lane >> 4;

  int bx, by, zsel = 0;
  if constexpr (QKT) {
    // supertile decode: column group g (8 cols), row-major within the group
    int id = blockIdx.x, g = 0;
    for (;;) { int sz = 36 + 8 * (56 - 8 * g); if (id < sz || g == 7) break; id -= sz; ++g; }
    int r, c;
    if (id < 36) {           // triangular head of the group (rows 0..7)
      int d = 0;
      while ((d + 1) * (d + 2) / 2 <= id) ++d;
      c = id - d * (d + 1) / 2; r = d;
    } else {                 // full rows (8 cols each)
      int q = id - 36; r = 8 + (q >> 3); c = q & 7;
    }
    by = 8 * g + r; bx = 8 * g + c;
  } else if constexpr (PVM) {
    by = 63 - ((int)blockIdx.x >> 4);     // longest rows first
    bx = ((int)blockIdx.x >> 1) & 7;
    zsel = (int)blockIdx.x & 1;
  } else {
    bx = blockIdx.x; by = blockIdx.y;
  }
  const int rowA0 = by * 128, col0 = bx * 128;

  int t0 = 0, NT = K >> 6;
  if constexpr (PVM) {
    const int half = by + 1;             // causal K-tiles = 2*(by+1); exact halves
    t0 = zsel * half; NT = t0 + half;
  }

  f32x4 acc[4][4] = {};

  for (int t = t0; t < NT; ++t) {
    const int k0 = t << 6;
#pragma unroll
    for (int i = 0; i < 4; ++i) {
      int s = tid + i * 256;
      int row = s >> 3, kc = s & 7;
      int kcs = kc ^ (row & 7);
      const ushort* ga = A + (size_t)(rowA0 + row) * (size_t)lda + (k0 + kcs * 8);
      const ushort* gb = Bt + (size_t)(col0 + row) * (size_t)ldb + (k0 + kcs * 8);
      __builtin_amdgcn_global_load_lds((glb_v*)ga, (lds_v*)(&Als[s * 8]), 16, 0, 0);
      __builtin_amdgcn_global_load_lds((glb_v*)gb, (lds_v*)(&Bls[s * 8]), 16, 0, 0);
    }
    __syncthreads();
#pragma unroll
    for (int kk = 0; kk < 2; ++kk) {
      bf16x8 af[4], bfr[4];
#pragma unroll
      for (int mi = 0; mi < 4; ++mi) {
        int r = wr + mi * 16 + ln15;
        int kc = kk * 4 + lhi;
        af[mi] = *reinterpret_cast<const bf16x8*>(&Als[(r * 64 + (kc ^ (r & 7)) * 8)]);
      }
#pragma unroll
      for (int ni = 0; ni < 4; ++ni) {
        int r = wc + ni * 16 + ln15;
        int kc = kk * 4 + lhi;
        bfr[ni] = *reinterpret_cast<const bf16x8*>(&Bls[(r * 64 + (kc ^ (r & 7)) * 8)]);
      }
#pragma unroll
      for (int mi = 0; mi < 4; ++mi)
#pragma unroll
        for (int ni = 0; ni < 4; ++ni)
          acc[mi][ni] = __builtin_amdgcn_mfma_f32_16x16x32_bf16(af[mi], bfr[ni], acc[mi][ni], 0, 0, 0);
    }
    __syncthreads();
  }

  // ---------------- epilogue: C col = lane&15 (+ni*16), row = lhi*4+j (+mi*16)
  if constexpr (QKT) {
#pragma unroll
    for (int mi = 0; mi < 4; ++mi) {
#pragma unroll
      for (int j = 0; j < 4; ++j) {
        const int row = rowA0 + wr + mi * 16 + lhi * 4 + j;
        float rs = 0.f;
        ushort pb[4];
#pragma unroll
        for (int ni = 0; ni < 4; ++ni) {
          const int col = col0 + wc + ni * 16 + ln15;
          float p = 0.f;
          if (col <= row) p = __expf(acc[mi][ni][j] * scale);
          pb[ni] = f2bf(p);
          rs += bf2f(pb[ni]);
        }
#pragma unroll
        for (int o = 1; o < 16; o <<= 1) rs += __shfl_xor(rs, o);
        if (ln15 == 0) atomicAdd(&lsum[row], rs);
#pragma unroll
        for (int ni = 0; ni < 4; ++ni) {
          const int col = col0 + wc + ni * 16 + ln15;
          ((ushort*)outp)[(size_t)row * (size_t)ldc + col] = pb[ni];
        }
      }
    }
  } else if constexpr (PVM) {
    ushort* dst = (ushort*)(zsel ? outp2 : outp);
#pragma unroll
    for (int mi = 0; mi < 4; ++mi) {
#pragma unroll
      for (int j = 0; j < 4; ++j) {
        const int row = rowA0 + wr + mi * 16 + lhi * 4 + j;
#pragma unroll
        for (int ni = 0; ni < 4; ++ni) {
          const int col = col0 + wc + ni * 16 + ln15;
          dst[(size_t)row * (size_t)ldc + col] = f2bf(acc[mi][ni][j]);
        }
      }
    }
  } else {
#pragma unroll
    for (int mi = 0; mi < 4; ++mi) {
#pragma unroll
      for (int j = 0; j < 4; ++j) {
        const int row = rowA0 + wr + mi * 16 + lhi * 4 + j;
#pragma unroll
        for (int ni = 0; ni < 4; ++ni) {
          const int colg = col0 + wc + ni * 16 + ln15;
          float val = acc[mi][ni][j] * scale;
          if constexpr (HAS_BIAS) val += bias[colg];
          int col = colg; size_t segoff = 0;
          if constexpr (SPLIT3) { int seg = colg >> 10; col = colg & 1023; segoff = (size_t)seg * (size_t)Tn * Cn; }
          if constexpr (OUT_BF16) ((ushort*)outp)[segoff + (size_t)row * (size_t)ldc + col] = f2bf(val);
          else                    ((float*)outp)[segoff + (size_t)row * (size_t)ldc + col] = val;
        }
      }
    }
  }
}

// ---------------------------------------------------------------- transpose (bf16), 64x64 tiles
__global__ __launch_bounds__(256) void transpose64(const ushort* __restrict__ in,
                                                   ushort* __restrict__ out,
                                                   int ldin, int ldout)
{
  __shared__ ushort tile[64][65];
  const int c0 = blockIdx.x * 64, r0 = blockIdx.y * 64;
  const int t = threadIdx.x;
#pragma unroll
  for (int i = t; i < 512; i += 256) {
    int r = i >> 3, kc = i & 7;
    uint4 v = *reinterpret_cast<const uint4*>(in + (size_t)(r0 + r) * ldin + c0 + kc * 8);
    const ushort* u = reinterpret_cast<const ushort*>(&v);
#pragma unroll
    for (int j = 0; j < 8; ++j) tile[r][kc * 8 + j] = u[j];
  }
  __syncthreads();
#pragma unroll
  for (int i = t; i < 512; i += 256) {
    int c = i >> 3, rc = i & 7;
    union { uint4 v; ushort u[8]; } pk;
#pragma unroll
    for (int j = 0; j < 8; ++j) pk.u[j] = tile[rc * 8 + j][c];
    *reinterpret_cast<uint4*>(out + (size_t)(c0 + c) * ldout + r0 + rc * 8) = pk.v;
  }
}

// ---------------------------------------------------------------- launch
extern "C" void kernel_launch(void* const* d_in, const int* in_sizes, int n_in,
                              void* d_out, int out_size, void* d_ws, size_t ws_size,
                              hipStream_t stream)
{
  (void)in_sizes; (void)n_in; (void)out_size; (void)ws_size;
  const float* x  = (const float*)d_in[0];
  const float* Wq = (const float*)d_in[1];
  const float* bq = (const float*)d_in[2];
  const float* Wk = (const float*)d_in[3];
  const float* bk = (const float*)d_in[4];
  const float* Wv = (const float*)d_in[5];
  const float* bv = (const float*)d_in[6];
  const float* Wp = (const float*)d_in[7];
  const float* bp = (const float*)d_in[8];

  char* w = (char*)d_ws;
  const size_t TC = (size_t)Tn * Cn * 2, CC = (size_t)Cn * Cn * 2;
  ushort* xb   = (ushort*)w; w += TC;                    // 16 MB
  ushort* Wqkv = (ushort*)w; w += 3 * CC;                // 6 MB
  ushort* wpb  = (ushort*)w; w += CC;                    // 2 MB
  float*  bqkv = (float*)w;  w += 16384;                 // 12 KB + pad
  float*  lsum = (float*)w;  w += 32768;                 // 32 KB
  ushort* Qb   = (ushort*)w; w += TC;                    // 16 MB  (PV partial0 after QKT)
  ushort* Kb   = (ushort*)w; w += TC;                    // 16 MB
  ushort* Vb   = (ushort*)w; w += TC;                    // 16 MB  (PV partial1 after transpose)
  ushort* Vt   = (ushort*)w; w += TC;                    // 16 MB
  ushort* Yb   = (ushort*)w; w += TC;                    // 16 MB
  ushort* S    = (ushort*)w; w += (size_t)Tn * Tn * 2;   // 128 MB

  cast_all<<<12292, 256, 0, stream>>>(x, Wq, Wk, Wv, Wp, bq, bk, bv,
                                      xb, Wqkv, wpb, bqkv, lsum);

  // QKV fused: split-3 epilogue -> Qb,Kb,Vb
  gemm_pl<true, true, false, false, true><<<dim3(24, 64), 256, 0, stream>>>(
      xb, Wqkv, bqkv, Qb, nullptr, nullptr, Cn, Cn, Cn, Cn, 1.0f);

  // V^T for the PV GEMM
  transpose64<<<dim3(Cn / 64, Tn / 64), 256, 0, stream>>>(Vb, Vt, Cn, Tn);

  // P' = exp(Q@K^T/32) (masked) + atomic row-sums l  (supertiled dispatch)
  gemm_pl<true, false, true, false, false><<<dim3(2080), 256, 0, stream>>>(
      Qb, Kb, nullptr, S, nullptr, lsum, Cn, Cn, Cn, Tn, 0.03125f);

  // PV split-K=2: bf16 partials -> Qb (z=0) / Vb (z=1); longest rows first
  gemm_pl<true, false, false, true, false><<<dim3(1024), 256, 0, stream>>>(
      S, Vt, nullptr, Qb, Vb, nullptr, Tn, Tn, Tn, Cn, 1.0f);

  // Yb = bf16((P0 + P1) / l)
  ydiv<<<4096, 256, 0, stream>>>(Qb, Vb, lsum, Yb);

  // out = Y @ Wp^T + bp (fp32 out)
  gemm_pl<false, true, false, false, false><<<dim3(8, 64), 256, 0, stream>>>(
      Yb, wpb, bp, d_out, nullptr, nullptr, Cn, Cn, Cn, Cn, 1.0f);
}